// Round 10
// baseline (109.476 us; speedup 1.0000x reference)
//
#include <hip/hip_runtime.h>
#include <hip/hip_bf16.h>

typedef __attribute__((ext_vector_type(8))) short short8;
typedef __attribute__((ext_vector_type(4))) float f32x4;
typedef __attribute__((ext_vector_type(4))) unsigned int u32x4;
typedef unsigned short u16;
typedef unsigned int   u32;
typedef unsigned long long u64;
typedef unsigned char  u8;

#define NN 8192
#define THRESH 0.1f

__device__ __forceinline__ u16 f2bf(float f){
  __hip_bfloat16 h = __float2bfloat16(f);
  u16 u; __builtin_memcpy(&u, &h, 2); return u;
}
__device__ __forceinline__ float bf2f(u16 h){
  u32 u = ((u32)h) << 16;
  return __builtin_bit_cast(float, u);
}

// ---- K1: normalize state rows; emit bf16 hi/lo split snHL[i][32] = [hi 0..15 | lo 0..15] ----
__global__ __launch_bounds__(256) void k_norm(const float* __restrict__ st, u16* __restrict__ snHL){
  int i = blockIdx.x*256 + threadIdx.x;
  const float4* s4 = reinterpret_cast<const float4*>(st + i*16);
  float4 v[4]; float ss = 0.f;
  #pragma unroll
  for (int q=0;q<4;q++){ v[q]=s4[q]; ss += v[q].x*v[q].x+v[q].y*v[q].y+v[q].z*v[q].z+v[q].w*v[q].w; }
  float inv = 1.0f/(sqrtf(ss) + 1e-12f);
  float f[16];
  #pragma unroll
  for (int q=0;q<4;q++){ f[4*q]=v[q].x*inv; f[4*q+1]=v[q].y*inv; f[4*q+2]=v[q].z*inv; f[4*q+3]=v[q].w*inv; }
  u16 hb[16], lb[16];
  #pragma unroll
  for (int k=0;k<16;k++){
    u16 h = f2bf(f[k]);
    hb[k] = h;
    lb[k] = f2bf(f[k] - bf2f(h));
  }
  u16* dst = snHL + (size_t)i*32;
  short8 o;
  #pragma unroll
  for (int e=0;e<8;e++) o[e] = (short)hb[e];
  *reinterpret_cast<short8*>(dst) = o;
  #pragma unroll
  for (int e=0;e<8;e++) o[e] = (short)hb[8+e];
  *reinterpret_cast<short8*>(dst+8) = o;
  #pragma unroll
  for (int e=0;e<8;e++) o[e] = (short)lb[e];
  *reinterpret_cast<short8*>(dst+16) = o;
  #pragma unroll
  for (int e=0;e<8;e++) o[e] = (short)lb[8+e];
  *reinterpret_cast<short8*>(dst+24) = o;
}

// ---- K2: MFMA mask. fid via hi/lo-split bf16 MFMA (exact to ~1e-7):
//   dot = A[hi;lo]·B1[hi;hi] + A[hi;lo]·B2[lo;lo]
// Block = 8 waves; wave = 32 i-rows x 1024 j. C layout (col=lane&15,row=4g+q) makes
// each __ballot 4 row-halfwords; assemble 32-bit words, store maskT[jw][i]. ----
__global__ __launch_bounds__(512) void k_maskMM(const u16* __restrict__ snHL, u32* __restrict__ maskT){
  __shared__ u16 sj[256*36];                 // 256 j-rows x stride 36 u16 (72B, bank-spread)
  int tid = threadIdx.x;
  int lane = tid & 63, wid = tid >> 6;
  int bx = (int)blockIdx.x;
  int i0b   = (bx >> 3) * 256;
  int jbase = (bx & 7) * 1024;
  int i0w = i0b + wid*32;
  int al = lane & 15, ag = lane >> 4;

  short8 afr[2];                             // A frags: [hi;lo] rows i0w+al, i0w+16+al
  afr[0] = *reinterpret_cast<const short8*>(snHL + (size_t)(i0w + al)*32 + ag*8);
  afr[1] = *reinterpret_cast<const short8*>(snHL + (size_t)(i0w + 16 + al)*32 + ag*8);

  int rq = lane & 3;                         // q-select for word assembly
  int rg = (lane >> 2) & 3;                  // g-select (16-bit halfword index)
  int fr8 = (lane >> 4) & 1;                 // frag-select (lanes 0-31 active for stores)

  #pragma unroll 1
  for (int chunk = 0; chunk < 4; ++chunk){
    int jc0 = jbase + chunk*256;
    {                                        // stage 256 rows x 64B (reg-staged, padded stride)
      int row = tid >> 1, half = tid & 1;
      const short8* src = reinterpret_cast<const short8*>(snHL + (size_t)(jc0 + row)*32 + half*16);
      short8 a = src[0], b = src[1];
      *reinterpret_cast<short8*>(sj + row*36 + half*16)     = a;
      *reinterpret_cast<short8*>(sj + row*36 + half*16 + 8) = b;
    }
    __syncthreads();
    #pragma unroll 1
    for (int jt = 0; jt < 8; ++jt){
      u64 bal[2][2][4];                      // [frag][tile][q], wave-uniform
      #pragma unroll
      for (int tile=0; tile<2; ++tile){
        const u16* bp = sj + (jt*32 + tile*16 + al)*36 + (ag&1)*8;
        short8 b1 = *reinterpret_cast<const short8*>(bp);       // [hi;hi]
        short8 b2 = *reinterpret_cast<const short8*>(bp + 16);  // [lo;lo]
        #pragma unroll
        for (int fr=0; fr<2; ++fr){
          f32x4 acc = {0.f,0.f,0.f,0.f};
          acc = __builtin_amdgcn_mfma_f32_16x16x32_bf16(afr[fr], b2, acc, 0,0,0);
          acc = __builtin_amdgcn_mfma_f32_16x16x32_bf16(afr[fr], b1, acc, 0,0,0);
          #pragma unroll
          for (int q=0;q<4;q++)
            bal[fr][tile][q] = __ballot(acc[q]*acc[q] >= THRESH);
        }
      }
      // assemble word for row ig = i0w + lane (lanes 0..31)
      u64 a0 = (rq&1) ? bal[0][0][1] : bal[0][0][0];
      u64 a1 = (rq&1) ? bal[0][0][3] : bal[0][0][2];
      u64 f0t0 = (rq&2) ? a1 : a0;
      u64 b0 = (rq&1) ? bal[1][0][1] : bal[1][0][0];
      u64 b1s= (rq&1) ? bal[1][0][3] : bal[1][0][2];
      u64 f1t0 = (rq&2) ? b1s : b0;
      u64 s0 = fr8 ? f1t0 : f0t0;
      u64 c0 = (rq&1) ? bal[0][1][1] : bal[0][1][0];
      u64 c1 = (rq&1) ? bal[0][1][3] : bal[0][1][2];
      u64 f0t1 = (rq&2) ? c1 : c0;
      u64 d0 = (rq&1) ? bal[1][1][1] : bal[1][1][0];
      u64 d1 = (rq&1) ? bal[1][1][3] : bal[1][1][2];
      u64 f1t1 = (rq&2) ? d1 : d0;
      u64 s1 = fr8 ? f1t1 : f0t1;
      u32 h0 = (u32)(s0 >> (rg*16)) & 0xffffu;
      u32 h1 = (u32)(s1 >> (rg*16)) & 0xffffu;
      u32 word = h0 | (h1 << 16);
      if (lane < 32){
        int jw = (jc0 + jt*32) >> 5;
        int ig = i0w + lane;
        u32 off = (u32)(ig - (jw<<5));
        if (off < 32u) word &= ~(1u<<off);   // no self-loop
        maskT[(size_t)jw*NN + ig] = word;
      }
    }
    __syncthreads();
  }
}

// ---- K2b: deg[i] via popcount; dinv = 1/(deg+eps) ----
__global__ __launch_bounds__(256) void k_deg(const u32* __restrict__ maskT, float* __restrict__ dinvF){
  __shared__ u32 red[256];
  int tid = threadIdx.x;
  int il = tid & 31, ws = tid >> 5;
  int i = blockIdx.x*32 + il;
  u32 s = 0;
  #pragma unroll 8
  for (int w = ws*32; w < ws*32 + 32; ++w) s += __popc(maskT[(size_t)w*NN + i]);
  red[tid] = s;
  __syncthreads();
  if (tid < 32){
    u32 tot = 0;
    #pragma unroll
    for (int g=0; g<8; ++g) tot += red[g*32 + tid];
    dinvF[i] = 1.0f/((float)tot + 1e-6f);
  }
}

// ---- K3: Yt[f][j] = dinv[j] * sum_k X[j,k]*W[f,k]  (bf16, j-contiguous) ----
__global__ __launch_bounds__(128) void k_ygemm(const float* __restrict__ X, const float* __restrict__ W,
                                               const float* __restrict__ dinvF, u16* __restrict__ Yt){
  int tid = threadIdx.x;
  int lane = tid & 63;
  int r = lane & 15, g = lane >> 4;
  int wj = tid >> 6;
  int f0 = blockIdx.x * 32;
  int j0 = blockIdx.y * 128 + wj * 64;
  f32x4 acc[2][4] = {};
  #pragma unroll
  for (int k0 = 0; k0 < 256; k0 += 32){
    short8 a[2], b[4];
    #pragma unroll
    for (int af=0; af<2; af++){
      const float* p = W + (f0 + af*16 + r)*256 + k0 + g*8;
      float4 u = reinterpret_cast<const float4*>(p)[0];
      float4 v = reinterpret_cast<const float4*>(p)[1];
      short8 tt;
      tt[0]=(short)f2bf(u.x); tt[1]=(short)f2bf(u.y); tt[2]=(short)f2bf(u.z); tt[3]=(short)f2bf(u.w);
      tt[4]=(short)f2bf(v.x); tt[5]=(short)f2bf(v.y); tt[6]=(short)f2bf(v.z); tt[7]=(short)f2bf(v.w);
      a[af] = tt;
    }
    #pragma unroll
    for (int bf=0; bf<4; bf++){
      const float* p = X + (j0 + bf*16 + r)*256 + k0 + g*8;
      float4 u = reinterpret_cast<const float4*>(p)[0];
      float4 v = reinterpret_cast<const float4*>(p)[1];
      short8 tt;
      tt[0]=(short)f2bf(u.x); tt[1]=(short)f2bf(u.y); tt[2]=(short)f2bf(u.z); tt[3]=(short)f2bf(u.w);
      tt[4]=(short)f2bf(v.x); tt[5]=(short)f2bf(v.y); tt[6]=(short)f2bf(v.z); tt[7]=(short)f2bf(v.w);
      b[bf] = tt;
    }
    #pragma unroll
    for (int af=0; af<2; af++)
      #pragma unroll
      for (int bf=0; bf<4; bf++)
        acc[af][bf] = __builtin_amdgcn_mfma_f32_16x16x32_bf16(a[af], b[bf], acc[af][bf], 0, 0, 0);
  }
  float ds[4];
  #pragma unroll
  for (int bf=0;bf<4;bf++) ds[bf] = dinvF[j0 + bf*16 + r];
  #pragma unroll
  for (int af=0; af<2; af++)
    #pragma unroll
    for (int bf=0; bf<4; bf++)
      #pragma unroll
      for (int q=0;q<4;q++)
        Yt[(f0 + af*16 + g*4 + q)*NN + j0 + bf*16 + r] = f2bf(acc[af][bf][q] * ds[bf]);
}

// ---- K4: partial[z] = M @ Y (bf16 out). Block m256 x n256(full), 8 waves wm2 x wn4,
// wave = m128 x n64. z=8, 16 K-steps, 3-buffer counted-vmcnt(5) DMA pipeline. ----
#define VMCNT(N) asm volatile("s_waitcnt vmcnt(" #N ")" ::: "memory")
__global__ __launch_bounds__(512, 2) void k_agg(const u16* __restrict__ Yt, const u32* __restrict__ maskT,
                                                u16* __restrict__ part){
  __shared__ u8  ldsB[3][32768];  // [buf][256 n-rows][64 k] bf16, chunk-XOR swizzle via source
  __shared__ u32 ldsM[3][512];    // [buf][row*2 + kword], 256 m-rows
  int tid = threadIdx.x;
  int lane = tid & 63, wid = tid >> 6;
  int r = lane & 15, g = lane >> 4;
  int wm = wid >> 2, wn = wid & 3;
  int bid = (int)blockIdx.x;
  int zz = bid & 7;
  int m0 = (bid >> 3) * 256;
  int kbase = zz * 1024;
  f32x4 acc[8][4] = {};

  const char* ytb[4];
  #pragma unroll
  for (int is=0; is<4; ++is){
    int rw = wid*32 + is*8 + (lane>>3);
    ytb[is] = (const char*)(Yt + ((size_t)rw << 13) + (size_t)kbase + (size_t)(((lane&7) ^ (rw&7))<<3));
  }
  const char* mkb = (const char*)(maskT + (size_t)((kbase>>5) + (lane&1))*NN + m0 + wid*32 + (lane>>1));

#define GSTAGE(BUF, T) do { \
    _Pragma("unroll") \
    for (int is=0; is<4; ++is) \
      __builtin_amdgcn_global_load_lds((const __attribute__((address_space(1))) void*)(ytb[is] + (T)*128), \
          (__attribute__((address_space(3))) void*)&ldsB[BUF][wid*4096 + is*1024], 16, 0, 0); \
    __builtin_amdgcn_global_load_lds((const __attribute__((address_space(1))) void*)(mkb + (size_t)(T)*65536), \
        (__attribute__((address_space(3))) void*)&ldsM[BUF][wid*64], 4, 0, 0); \
  } while(0)

#define COMPUTE(BUF) do { \
    short8 bfrag[2][4]; \
    _Pragma("unroll") \
    for (int kk=0; kk<2; ++kk) \
      _Pragma("unroll") \
      for (int nf=0; nf<4; ++nf){ \
        int row = wn*64 + nf*16 + r; \
        bfrag[kk][nf] = *reinterpret_cast<const short8*>(&ldsB[BUF][row*128 + (((kk*4+g) ^ (row&7))<<4)]); \
      } \
    __builtin_amdgcn_s_setprio(1); \
    _Pragma("unroll") \
    for (int mf=0; mf<8; ++mf){ \
      int rowm = wm*128 + mf*16 + r; \
      u64 mw = *reinterpret_cast<const u64*>(&ldsM[BUF][rowm*2]); \
      _Pragma("unroll") \
      for (int kk=0; kk<2; ++kk){ \
        u32 byte = ((u32)(mw >> (kk*32)) >> (g*8)) & 0xffu; \
        u32 x = byte * 0x8001u; \
        u32x4 wv; \
        _Pragma("unroll") \
        for (int pp=0; pp<4; ++pp) wv[pp] = ((x >> (2*pp)) & 0x00010001u) * 0x3F80u; \
        short8 a = __builtin_bit_cast(short8, wv); \
        _Pragma("unroll") \
        for (int nf=0; nf<4; ++nf) \
          acc[mf][nf] = __builtin_amdgcn_mfma_f32_16x16x32_bf16(a, bfrag[kk][nf], acc[mf][nf], 0, 0, 0); \
      } \
    } \
    __builtin_amdgcn_s_setprio(0); \
  } while(0)

#define BODY(CB, SB, T) do { \
    GSTAGE(SB, (T)+2); \
    COMPUTE(CB); \
    VMCNT(5); \
    __builtin_amdgcn_s_barrier(); \
  } while(0)

  GSTAGE(0, 0);
  GSTAGE(1, 1);
  VMCNT(5);
  __builtin_amdgcn_s_barrier();

  #pragma unroll 1
  for (int t = 0; t < 12; t += 3){
    BODY(0, 2, t);
    BODY(1, 0, t+1);
    BODY(2, 1, t+2);
  }
  BODY(0, 2, 12);
  BODY(1, 0, 13);
  COMPUTE(2);
  VMCNT(0);
  __builtin_amdgcn_s_barrier();
  COMPUTE(0);

#undef GSTAGE
#undef COMPUTE
#undef BODY

  u16* dst = part + (size_t)zz * (NN*256);
  #pragma unroll
  for (int mf=0; mf<8; mf++)
    #pragma unroll
    for (int nf=0; nf<4; nf++)
      #pragma unroll
      for (int q=0;q<4;q++){
        int row = m0 + wm*128 + mf*16 + g*4 + q;
        int col = wn*64 + nf*16 + r;
        dst[row*256 + col] = f2bf(acc[mf][nf][q]);
      }
}

// ---- K5: out = bias + sum_z bf16 partial[z] ----
__global__ __launch_bounds__(256) void k_reduce(const u16* __restrict__ part, const float* __restrict__ bias,
                                                float* __restrict__ out){
  int i = blockIdx.x*256 + threadIdx.x;
  float4 bb = reinterpret_cast<const float4*>(bias)[i & 63];
  float a0 = bb.x, a1 = bb.y, a2 = bb.z, a3 = bb.w;
  #pragma unroll
  for (int z=0; z<8; ++z){
    u64 v = *reinterpret_cast<const u64*>(part + (size_t)z*2097152 + (size_t)i*4);
    a0 += bf2f((u16)(v      ));
    a1 += bf2f((u16)(v >> 16));
    a2 += bf2f((u16)(v >> 32));
    a3 += bf2f((u16)(v >> 48));
  }
  float4 o; o.x=a0; o.y=a1; o.z=a2; o.w=a3;
  reinterpret_cast<float4*>(out)[i] = o;
}

extern "C" void kernel_launch(void* const* d_in, const int* in_sizes, int n_in,
                              void* d_out, int out_size, void* d_ws, size_t ws_size,
                              hipStream_t stream) {
  const float* X    = (const float*)d_in[0];
  const float* S    = (const float*)d_in[1];
  const float* W    = (const float*)d_in[2];
  const float* bias = (const float*)d_in[3];
  float* out = (float*)d_out;
  char* ws = (char*)d_ws;
  u32*   maskT = (u32*)  (ws + 0);         //  8 MiB  [256 jwords][8192 i]
  u16*   Yt    = (u16*)  (ws + 8388608);   //  4 MiB  bf16 [256 f][8192 j]
  u16*   snHL  = (u16*)  (ws + 12582912);  // 512 KiB bf16 hi/lo split states
  float* dinvF = (float*)(ws + 13107200);  //  32 KiB
  u16*   part  = (u16*)  (ws + 13139968);  //  32 MiB bf16 [8][8192][256]

  k_norm  <<<dim3(32),   dim3(256), 0, stream>>>(S, snHL);
  k_maskMM<<<dim3(256),  dim3(512), 0, stream>>>(snHL, maskT);
  k_deg   <<<dim3(256),  dim3(256), 0, stream>>>(maskT, dinvF);
  k_ygemm <<<dim3(8,64), dim3(128), 0, stream>>>(X, W, dinvF, Yt);
  k_agg   <<<dim3(256),  dim3(512), 0, stream>>>(Yt, maskT, part);
  k_reduce<<<dim3(2048), dim3(256), 0, stream>>>(part, bias, out);
}

// Round 11
// 98.811 us; speedup vs baseline: 1.1079x; 1.1079x over previous
//
#include <hip/hip_runtime.h>
#include <hip/hip_bf16.h>

typedef __attribute__((ext_vector_type(8))) short short8;
typedef __attribute__((ext_vector_type(4))) float f32x4;
typedef __attribute__((ext_vector_type(4))) unsigned int u32x4;
typedef unsigned short u16;
typedef unsigned int   u32;
typedef unsigned long long u64;
typedef unsigned char  u8;

#define NN 8192
#define THRESH 0.1f

__device__ __forceinline__ u16 f2bf(float f){
  __hip_bfloat16 h = __float2bfloat16(f);
  u16 u; __builtin_memcpy(&u, &h, 2); return u;
}
__device__ __forceinline__ float bf2f(u16 h){
  u32 u = ((u32)h) << 16;
  return __builtin_bit_cast(float, u);
}

// ---- K1: normalize state rows ----
__global__ __launch_bounds__(256) void k_norm(const float* __restrict__ st, float* __restrict__ sn){
  int i = blockIdx.x*256 + threadIdx.x;
  const float4* s4 = reinterpret_cast<const float4*>(st + i*16);
  float4 v[4]; float ss = 0.f;
  #pragma unroll
  for (int q=0;q<4;q++){ v[q]=s4[q]; ss += v[q].x*v[q].x+v[q].y*v[q].y+v[q].z*v[q].z+v[q].w*v[q].w; }
  float inv = 1.0f/(sqrtf(ss) + 1e-12f);
  float4* d4 = reinterpret_cast<float4*>(sn + i*16);
  #pragma unroll
  for (int q=0;q<4;q++){ float4 o; o.x=v[q].x*inv; o.y=v[q].y*inv; o.z=v[q].z*inv; o.w=v[q].w*inv; d4[q]=o; }
}

// ---- K2: symmetric tile mask. Wave-tile = 256 i (4 rows/lane) x 32 j, upper-tri. ----
__global__ __launch_bounds__(256) void k_maskT5(const float* __restrict__ sn, u32* __restrict__ maskT){
  __shared__ float sjtA[4*32*20];
  int tid  = threadIdx.x;
  int lane = tid & 63;
  int wid  = tid >> 6;
  int t = __builtin_amdgcn_readfirstlane((int)blockIdx.x*4 + wid);  // 0..4223
  int k = 0;
  while (4*(k+1)*(64-k) <= t) ++k;
  int I0 = __builtin_amdgcn_readfirstlane(k << 8);
  int jb = 8*k + (t - 4*k*(65-k));
  int J0 = __builtin_amdgcn_readfirstlane(jb << 5);

  float* sjt = sjtA + wid*640;
  #pragma unroll
  for (int s=0;s<2;s++){
    int c2 = lane + 64*s;
    int row = c2 >> 2, q = c2 & 3;
    float4 v = *reinterpret_cast<const float4*>(sn + (J0+row)*16 + q*4);
    *reinterpret_cast<float4*>(sjt + row*20 + q*4) = v;
  }

  float si[4][16];
  #pragma unroll
  for (int c=0;c<4;c++){
    #pragma unroll
    for (int q=0;q<4;q++){
      float4 v = reinterpret_cast<const float4*>(sn + (I0 + 64*c + lane)*16)[q];
      si[c][4*q]=v.x; si[c][4*q+1]=v.y; si[c][4*q+2]=v.z; si[c][4*q+3]=v.w;
    }
  }

  u32 roww[4] = {0,0,0,0};
  u32 colw[8] = {0,0,0,0,0,0,0,0};
  #pragma unroll 2
  for (int j2=0; j2<32; ++j2){
    const float* sp = sjt + j2*20;
    float4 p0 = *reinterpret_cast<const float4*>(sp);
    float4 p1 = *reinterpret_cast<const float4*>(sp+4);
    float4 p2 = *reinterpret_cast<const float4*>(sp+8);
    float4 p3 = *reinterpret_cast<const float4*>(sp+12);
    bool me = (lane == j2);
    #pragma unroll
    for (int c=0;c<4;c++){
      float d0 = p0.x*si[c][0]  + p0.y*si[c][1]  + p0.z*si[c][2]  + p0.w*si[c][3];
      float d1 = p1.x*si[c][4]  + p1.y*si[c][5]  + p1.z*si[c][6]  + p1.w*si[c][7];
      float d2 = p2.x*si[c][8]  + p2.y*si[c][9]  + p2.z*si[c][10] + p2.w*si[c][11];
      float d3 = p3.x*si[c][12] + p3.y*si[c][13] + p3.z*si[c][14] + p3.w*si[c][15];
      float d  = (d0+d1)+(d2+d3);
      bool pr = (d*d >= THRESH);
      u64 bal = __ballot(pr);
      roww[c] |= pr ? (1u<<j2) : 0u;
      colw[2*c]   = me ? (u32)bal       : colw[2*c];
      colw[2*c+1] = me ? (u32)(bal>>32) : colw[2*c+1];
    }
  }

  #pragma unroll
  for (int c=0;c<4;c++){
    u32 rel = (u32)(I0 + 64*c + lane - J0);
    if (rel < 32u) roww[c] &= ~(1u<<rel);
  }
  u32 off = (u32)(J0 + lane - I0);
  #pragma unroll
  for (int w=0;w<8;w++)
    colw[w] &= ~(((off>>5) == (u32)w) ? (1u<<(off&31)) : 0u);

  #pragma unroll
  for (int c=0;c<4;c++)
    maskT[(size_t)jb*NN + I0 + 64*c + lane] = roww[c];
  if (lane < 32){
    #pragma unroll
    for (int w=0;w<8;w++)
      maskT[(size_t)((I0>>5)+w)*NN + J0 + lane] = colw[w];
  }
}

// ---- K2b: deg[i] via popcount; dinv = 1/(deg+eps) ----
__global__ __launch_bounds__(256) void k_deg(const u32* __restrict__ maskT, float* __restrict__ dinvF){
  __shared__ u32 red[256];
  int tid = threadIdx.x;
  int il = tid & 31, ws = tid >> 5;
  int i = blockIdx.x*32 + il;
  u32 s = 0;
  #pragma unroll 8
  for (int w = ws*32; w < ws*32 + 32; ++w) s += __popc(maskT[(size_t)w*NN + i]);
  red[tid] = s;
  __syncthreads();
  if (tid < 32){
    u32 tot = 0;
    #pragma unroll
    for (int g=0; g<8; ++g) tot += red[g*32 + tid];
    dinvF[i] = 1.0f/((float)tot + 1e-6f);
  }
}

// ---- K3: Yt[f][j] = dinv[j] * sum_k X[j,k]*W[f,k]  (bf16, j-contiguous) ----
__global__ __launch_bounds__(128) void k_ygemm(const float* __restrict__ X, const float* __restrict__ W,
                                               const float* __restrict__ dinvF, u16* __restrict__ Yt){
  int tid = threadIdx.x;
  int lane = tid & 63;
  int r = lane & 15, g = lane >> 4;
  int wj = tid >> 6;
  int f0 = blockIdx.x * 32;
  int j0 = blockIdx.y * 128 + wj * 64;
  f32x4 acc[2][4] = {};
  #pragma unroll
  for (int k0 = 0; k0 < 256; k0 += 32){
    short8 a[2], b[4];
    #pragma unroll
    for (int af=0; af<2; af++){
      const float* p = W + (f0 + af*16 + r)*256 + k0 + g*8;
      float4 u = reinterpret_cast<const float4*>(p)[0];
      float4 v = reinterpret_cast<const float4*>(p)[1];
      short8 tt;
      tt[0]=(short)f2bf(u.x); tt[1]=(short)f2bf(u.y); tt[2]=(short)f2bf(u.z); tt[3]=(short)f2bf(u.w);
      tt[4]=(short)f2bf(v.x); tt[5]=(short)f2bf(v.y); tt[6]=(short)f2bf(v.z); tt[7]=(short)f2bf(v.w);
      a[af] = tt;
    }
    #pragma unroll
    for (int bf=0; bf<4; bf++){
      const float* p = X + (j0 + bf*16 + r)*256 + k0 + g*8;
      float4 u = reinterpret_cast<const float4*>(p)[0];
      float4 v = reinterpret_cast<const float4*>(p)[1];
      short8 tt;
      tt[0]=(short)f2bf(u.x); tt[1]=(short)f2bf(u.y); tt[2]=(short)f2bf(u.z); tt[3]=(short)f2bf(u.w);
      tt[4]=(short)f2bf(v.x); tt[5]=(short)f2bf(v.y); tt[6]=(short)f2bf(v.z); tt[7]=(short)f2bf(v.w);
      b[bf] = tt;
    }
    #pragma unroll
    for (int af=0; af<2; af++)
      #pragma unroll
      for (int bf=0; bf<4; bf++)
        acc[af][bf] = __builtin_amdgcn_mfma_f32_16x16x32_bf16(a[af], b[bf], acc[af][bf], 0, 0, 0);
  }
  float ds[4];
  #pragma unroll
  for (int bf=0;bf<4;bf++) ds[bf] = dinvF[j0 + bf*16 + r];
  #pragma unroll
  for (int af=0; af<2; af++)
    #pragma unroll
    for (int bf=0; bf<4; bf++)
      #pragma unroll
      for (int q=0;q<4;q++)
        Yt[(f0 + af*16 + g*4 + q)*NN + j0 + bf*16 + r] = f2bf(acc[af][bf][q] * ds[bf]);
}

// ---- K4: partial[z] = M @ Y (bf16 out). Block m256 x n128, 8 waves wm4 x wn2,
// wave = m64 x n64 (nf4 keeps expansion amortized; mf4 halves acc VGPR).
// Grid 512 = 2 blocks/CU -> 4 waves/SIMD from DECOUPLED blocks (barrier overlap).
// 3-buffer depth-2 counted-vmcnt(3) DMA pipeline, 54KB LDS. ----
#define VMCNT(N) asm volatile("s_waitcnt vmcnt(" #N ")" ::: "memory")
__global__ __launch_bounds__(512, 4) void k_agg(const u16* __restrict__ Yt, const u32* __restrict__ maskT,
                                                u16* __restrict__ part){
  __shared__ u8  ldsB[3][16384];  // [buf][128 n-rows][64 k] bf16, chunk-XOR swizzle via source
  __shared__ u32 ldsM[3][512];    // [buf][256 m-rows x 2 words interleaved]
  int tid = threadIdx.x;
  int lane = tid & 63, wid = tid >> 6;
  int r = lane & 15, g = lane >> 4;
  int wm = wid >> 1, wn = wid & 1;              // wave = m64 x n64
  int bid = (int)blockIdx.x;
  int gq = bid & 15;                             // (n-half, zz) group; XCD = gq&7
  int m0 = (bid >> 4) * 256;
  int n0 = (gq & 1) * 128;
  int zz = gq >> 1;
  int kbase = zz * 1024;
  f32x4 acc[4][4] = {};

  // per-lane global source addresses at step T=0 (source pre-swizzled, linear LDS dest)
  const char* ytb[2];
  #pragma unroll
  for (int is=0; is<2; ++is){
    int rw = wid*16 + is*8 + (lane>>3);          // 0..127 (n-local row)
    ytb[is] = (const char*)(Yt + ((size_t)(n0+rw) << 13) + (size_t)kbase + (size_t)(((lane&7) ^ (rw&7))<<3));
  }
  const char* mkb = (const char*)(maskT + (size_t)((kbase>>5) + (lane&1))*NN + m0 + wid*32 + (lane>>1));

#define GSTAGE(BUF, T) do { \
    _Pragma("unroll") \
    for (int is=0; is<2; ++is) \
      __builtin_amdgcn_global_load_lds((const __attribute__((address_space(1))) void*)(ytb[is] + (T)*128), \
          (__attribute__((address_space(3))) void*)&ldsB[BUF][wid*2048 + is*1024], 16, 0, 0); \
    __builtin_amdgcn_global_load_lds((const __attribute__((address_space(1))) void*)(mkb + (size_t)(T)*65536), \
        (__attribute__((address_space(3))) void*)&ldsM[BUF][wid*64], 4, 0, 0); \
  } while(0)

#define COMPUTE(BUF) do { \
    short8 bfrag[2][4]; \
    _Pragma("unroll") \
    for (int kk=0; kk<2; ++kk) \
      _Pragma("unroll") \
      for (int nf=0; nf<4; ++nf){ \
        int row = wn*64 + nf*16 + r; \
        bfrag[kk][nf] = *reinterpret_cast<const short8*>(&ldsB[BUF][row*128 + (((kk*4+g) ^ (row&7))<<4)]); \
      } \
    __builtin_amdgcn_s_setprio(1); \
    _Pragma("unroll") \
    for (int mf=0; mf<4; ++mf){ \
      int rowm = wm*64 + mf*16 + r; \
      u64 mw = *reinterpret_cast<const u64*>(&ldsM[BUF][rowm*2]); \
      _Pragma("unroll") \
      for (int kk=0; kk<2; ++kk){ \
        u32 byte = ((u32)(mw >> (kk*32)) >> (g*8)) & 0xffu; \
        u32 x = byte * 0x8001u; \
        u32x4 wv; \
        _Pragma("unroll") \
        for (int pp=0; pp<4; ++pp) wv[pp] = ((x >> (2*pp)) & 0x00010001u) * 0x3F80u; \
        short8 a = __builtin_bit_cast(short8, wv); \
        _Pragma("unroll") \
        for (int nf=0; nf<4; ++nf) \
          acc[mf][nf] = __builtin_amdgcn_mfma_f32_16x16x32_bf16(a, bfrag[kk][nf], acc[mf][nf], 0, 0, 0); \
      } \
    } \
    __builtin_amdgcn_s_setprio(0); \
  } while(0)

#define BODY(CB, SB, T) do { \
    GSTAGE(SB, (T)+2); \
    COMPUTE(CB); \
    VMCNT(3); \
    __builtin_amdgcn_s_barrier(); \
  } while(0)

  GSTAGE(0, 0);
  GSTAGE(1, 1);
  VMCNT(3);                       // stage(0) landed; stage(1) in flight
  __builtin_amdgcn_s_barrier();

  #pragma unroll 1
  for (int t = 0; t < 12; t += 3){
    BODY(0, 2, t);
    BODY(1, 0, t+1);
    BODY(2, 1, t+2);
  }
  BODY(0, 2, 12);                 // stages T=14, computes 12
  BODY(1, 0, 13);                 // stages T=15, computes 13
  COMPUTE(2);                     // tile 14
  VMCNT(0);                       // stage(15) fully landed (per-wave)
  __builtin_amdgcn_s_barrier();   // ...and cross-wave
  COMPUTE(0);                     // tile 15

#undef GSTAGE
#undef COMPUTE
#undef BODY

  u16* dst = part + (size_t)zz * (NN*256);
  #pragma unroll
  for (int mf=0; mf<4; mf++)
    #pragma unroll
    for (int nf=0; nf<4; nf++)
      #pragma unroll
      for (int q=0;q<4;q++){
        int row = m0 + wm*64 + mf*16 + g*4 + q;
        int col = n0 + wn*64 + nf*16 + r;
        dst[row*256 + col] = f2bf(acc[mf][nf][q]);
      }
}

// ---- K5: out = bias + sum_z bf16 partial[z] ----
__global__ __launch_bounds__(256) void k_reduce(const u16* __restrict__ part, const float* __restrict__ bias,
                                                float* __restrict__ out){
  int i = blockIdx.x*256 + threadIdx.x;
  float4 bb = reinterpret_cast<const float4*>(bias)[i & 63];
  float a0 = bb.x, a1 = bb.y, a2 = bb.z, a3 = bb.w;
  #pragma unroll
  for (int z=0; z<8; ++z){
    u64 v = *reinterpret_cast<const u64*>(part + (size_t)z*2097152 + (size_t)i*4);
    a0 += bf2f((u16)(v      ));
    a1 += bf2f((u16)(v >> 16));
    a2 += bf2f((u16)(v >> 32));
    a3 += bf2f((u16)(v >> 48));
  }
  float4 o; o.x=a0; o.y=a1; o.z=a2; o.w=a3;
  reinterpret_cast<float4*>(out)[i] = o;
}

extern "C" void kernel_launch(void* const* d_in, const int* in_sizes, int n_in,
                              void* d_out, int out_size, void* d_ws, size_t ws_size,
                              hipStream_t stream) {
  const float* X    = (const float*)d_in[0];
  const float* S    = (const float*)d_in[1];
  const float* W    = (const float*)d_in[2];
  const float* bias = (const float*)d_in[3];
  float* out = (float*)d_out;
  char* ws = (char*)d_ws;
  u32*   maskT = (u32*)  (ws + 0);         //  8 MiB  [256 jwords][8192 i]
  u16*   Yt    = (u16*)  (ws + 8388608);   //  4 MiB  bf16 [256 f][8192 j]
  float* snorm = (float*)(ws + 12582912);  // 512 KiB
  float* dinvF = (float*)(ws + 13107200);  //  32 KiB
  u16*   part  = (u16*)  (ws + 13139968);  //  32 MiB bf16 [8][8192][256]

  k_norm  <<<dim3(32),   dim3(256), 0, stream>>>(S, snorm);
  k_maskT5<<<dim3(1056), dim3(256), 0, stream>>>(snorm, maskT);
  k_deg   <<<dim3(256),  dim3(256), 0, stream>>>(maskT, dinvF);
  k_ygemm <<<dim3(8,64), dim3(128), 0, stream>>>(X, W, dinvF, Yt);
  k_agg   <<<dim3(512),  dim3(512), 0, stream>>>(Yt, maskT, part);
  k_reduce<<<dim3(2048), dim3(256), 0, stream>>>(part, bias, out);
}

// Round 12
// 90.106 us; speedup vs baseline: 1.2150x; 1.0966x over previous
//
#include <hip/hip_runtime.h>
#include <hip/hip_bf16.h>

typedef __attribute__((ext_vector_type(8))) short short8;
typedef __attribute__((ext_vector_type(4))) float f32x4;
typedef __attribute__((ext_vector_type(4))) unsigned int u32x4;
typedef unsigned short u16;
typedef unsigned int   u32;
typedef unsigned long long u64;
typedef unsigned char  u8;

#define NN 8192
#define THRESH 0.1f

__device__ __forceinline__ u16 f2bf(float f){
  __hip_bfloat16 h = __float2bfloat16(f);
  u16 u; __builtin_memcpy(&u, &h, 2); return u;
}
__device__ __forceinline__ float bf2f(u16 h){
  u32 u = ((u32)h) << 16;
  return __builtin_bit_cast(float, u);
}

// ---- K1: normalize state rows; emit bf16 hi/lo split snHL[i][32] = [hi 0..15 | lo 0..15] ----
__global__ __launch_bounds__(256) void k_norm(const float* __restrict__ st, u16* __restrict__ snHL){
  int i = blockIdx.x*256 + threadIdx.x;
  const float4* s4 = reinterpret_cast<const float4*>(st + i*16);
  float4 v[4]; float ss = 0.f;
  #pragma unroll
  for (int q=0;q<4;q++){ v[q]=s4[q]; ss += v[q].x*v[q].x+v[q].y*v[q].y+v[q].z*v[q].z+v[q].w*v[q].w; }
  float inv = 1.0f/(sqrtf(ss) + 1e-12f);
  float f[16];
  #pragma unroll
  for (int q=0;q<4;q++){ f[4*q]=v[q].x*inv; f[4*q+1]=v[q].y*inv; f[4*q+2]=v[q].z*inv; f[4*q+3]=v[q].w*inv; }
  u16 hb[16], lb[16];
  #pragma unroll
  for (int k=0;k<16;k++){
    u16 h = f2bf(f[k]);
    hb[k] = h;
    lb[k] = f2bf(f[k] - bf2f(h));
  }
  u16* dst = snHL + (size_t)i*32;
  short8 o;
  #pragma unroll
  for (int e=0;e<8;e++) o[e] = (short)hb[e];
  *reinterpret_cast<short8*>(dst) = o;
  #pragma unroll
  for (int e=0;e<8;e++) o[e] = (short)hb[8+e];
  *reinterpret_cast<short8*>(dst+8) = o;
  #pragma unroll
  for (int e=0;e<8;e++) o[e] = (short)lb[e];
  *reinterpret_cast<short8*>(dst+16) = o;
  #pragma unroll
  for (int e=0;e<8;e++) o[e] = (short)lb[8+e];
  *reinterpret_cast<short8*>(dst+24) = o;
}

// ---- K2: swapped-operand MFMA mask. A = s_j rows (hi|lo natural), B = s_i rows
// (b1=[hi|hi], b2=[lo|lo], preloaded). C[col=lane&15 -> i, row=4g+q -> j]: j-bits land
// per-lane; pack in-register (4 VALU/bit), OR across g via 2 shfl_xor, store lanes 0-15.
// dot = A·b2 + A·b1 (b2 first, matching R10's verified order) = exact hi/lo split (~1e-7).
// No LDS, no barriers. 1024 blocks x 4 waves; wave = 16 i x 1024 j. ----
__global__ __launch_bounds__(256) void k_maskM2(const u16* __restrict__ snHL, u32* __restrict__ maskT){
  int tid = threadIdx.x;
  int lane = tid & 63, wid = tid >> 6;
  int n = lane & 15, g = lane >> 4;
  int bid = (int)blockIdx.x;                   // 0..1023
  int i0 = (bid >> 3) * 64 + wid * 16;
  int jc = (bid & 7) * 1024;
  int ii = i0 + n;

  const u16* brow = snHL + (size_t)ii*32;
  short8 b1 = *reinterpret_cast<const short8*>(brow + (g&1)*8);        // [hi|hi] k-slice
  short8 b2 = *reinterpret_cast<const short8*>(brow + 16 + (g&1)*8);   // [lo|lo] k-slice

  u32 bitc[2][4];
  #pragma unroll
  for (int h=0; h<2; ++h)
    #pragma unroll
    for (int q=0; q<4; ++q) bitc[h][q] = 1u << (h*16 + 4*g + q);

  #pragma unroll 2
  for (int jw2 = 0; jw2 < 32; ++jw2){
    int j0 = jc + jw2*32;
    u32 w = 0;
    #pragma unroll
    for (int h=0; h<2; ++h){
      short8 a = *reinterpret_cast<const short8*>(snHL + (size_t)(j0 + h*16 + n)*32 + g*8); // [hi|lo]
      f32x4 acc = {0.f,0.f,0.f,0.f};
      acc = __builtin_amdgcn_mfma_f32_16x16x32_bf16(a, b2, acc, 0, 0, 0);
      acc = __builtin_amdgcn_mfma_f32_16x16x32_bf16(a, b1, acc, 0, 0, 0);
      #pragma unroll
      for (int q=0;q<4;q++){
        float d = acc[q];
        w |= (d*d >= THRESH) ? bitc[h][q] : 0u;
      }
    }
    w |= __shfl_xor(w, 16);
    w |= __shfl_xor(w, 32);
    int jw = j0 >> 5;
    if ((ii >> 5) == jw) w &= ~(1u << (ii & 31));   // no self-loop
    if (lane < 16) maskT[(size_t)jw*NN + ii] = w;
  }
}

// ---- K2b: deg[i] via popcount; dinv = 1/(deg+eps) ----
__global__ __launch_bounds__(256) void k_deg(const u32* __restrict__ maskT, float* __restrict__ dinvF){
  __shared__ u32 red[256];
  int tid = threadIdx.x;
  int il = tid & 31, ws = tid >> 5;
  int i = blockIdx.x*32 + il;
  u32 s = 0;
  #pragma unroll 8
  for (int w = ws*32; w < ws*32 + 32; ++w) s += __popc(maskT[(size_t)w*NN + i]);
  red[tid] = s;
  __syncthreads();
  if (tid < 32){
    u32 tot = 0;
    #pragma unroll
    for (int g=0; g<8; ++g) tot += red[g*32 + tid];
    dinvF[i] = 1.0f/((float)tot + 1e-6f);
  }
}

// ---- K3: Yt[f][j] = dinv[j] * sum_k X[j,k]*W[f,k]  (bf16, j-contiguous) ----
__global__ __launch_bounds__(128) void k_ygemm(const float* __restrict__ X, const float* __restrict__ W,
                                               const float* __restrict__ dinvF, u16* __restrict__ Yt){
  int tid = threadIdx.x;
  int lane = tid & 63;
  int r = lane & 15, g = lane >> 4;
  int wj = tid >> 6;
  int f0 = blockIdx.x * 32;
  int j0 = blockIdx.y * 128 + wj * 64;
  f32x4 acc[2][4] = {};
  #pragma unroll
  for (int k0 = 0; k0 < 256; k0 += 32){
    short8 a[2], b[4];
    #pragma unroll
    for (int af=0; af<2; af++){
      const float* p = W + (f0 + af*16 + r)*256 + k0 + g*8;
      float4 u = reinterpret_cast<const float4*>(p)[0];
      float4 v = reinterpret_cast<const float4*>(p)[1];
      short8 tt;
      tt[0]=(short)f2bf(u.x); tt[1]=(short)f2bf(u.y); tt[2]=(short)f2bf(u.z); tt[3]=(short)f2bf(u.w);
      tt[4]=(short)f2bf(v.x); tt[5]=(short)f2bf(v.y); tt[6]=(short)f2bf(v.z); tt[7]=(short)f2bf(v.w);
      a[af] = tt;
    }
    #pragma unroll
    for (int bf=0; bf<4; bf++){
      const float* p = X + (j0 + bf*16 + r)*256 + k0 + g*8;
      float4 u = reinterpret_cast<const float4*>(p)[0];
      float4 v = reinterpret_cast<const float4*>(p)[1];
      short8 tt;
      tt[0]=(short)f2bf(u.x); tt[1]=(short)f2bf(u.y); tt[2]=(short)f2bf(u.z); tt[3]=(short)f2bf(u.w);
      tt[4]=(short)f2bf(v.x); tt[5]=(short)f2bf(v.y); tt[6]=(short)f2bf(v.z); tt[7]=(short)f2bf(v.w);
      b[bf] = tt;
    }
    #pragma unroll
    for (int af=0; af<2; af++)
      #pragma unroll
      for (int bf=0; bf<4; bf++)
        acc[af][bf] = __builtin_amdgcn_mfma_f32_16x16x32_bf16(a[af], b[bf], acc[af][bf], 0, 0, 0);
  }
  float ds[4];
  #pragma unroll
  for (int bf=0;bf<4;bf++) ds[bf] = dinvF[j0 + bf*16 + r];
  #pragma unroll
  for (int af=0; af<2; af++)
    #pragma unroll
    for (int bf=0; bf<4; bf++)
      #pragma unroll
      for (int q=0;q<4;q++)
        Yt[(f0 + af*16 + g*4 + q)*NN + j0 + bf*16 + r] = f2bf(acc[af][bf][q] * ds[bf]);
}

// ---- K4: partial[z] = M @ Y (bf16 out). Block m256 x n128, 8 waves wm4 x wn2,
// wave = m64 x n64. Grid 512 = 2 blocks/CU. 3-buffer depth-2 counted-vmcnt(3). ----
#define VMCNT(N) asm volatile("s_waitcnt vmcnt(" #N ")" ::: "memory")
__global__ __launch_bounds__(512, 4) void k_agg(const u16* __restrict__ Yt, const u32* __restrict__ maskT,
                                                u16* __restrict__ part){
  __shared__ u8  ldsB[3][16384];
  __shared__ u32 ldsM[3][512];
  int tid = threadIdx.x;
  int lane = tid & 63, wid = tid >> 6;
  int r = lane & 15, g = lane >> 4;
  int wm = wid >> 1, wn = wid & 1;
  int bid = (int)blockIdx.x;
  int gq = bid & 15;
  int m0 = (bid >> 4) * 256;
  int n0 = (gq & 1) * 128;
  int zz = gq >> 1;
  int kbase = zz * 1024;
  f32x4 acc[4][4] = {};

  const char* ytb[2];
  #pragma unroll
  for (int is=0; is<2; ++is){
    int rw = wid*16 + is*8 + (lane>>3);
    ytb[is] = (const char*)(Yt + ((size_t)(n0+rw) << 13) + (size_t)kbase + (size_t)(((lane&7) ^ (rw&7))<<3));
  }
  const char* mkb = (const char*)(maskT + (size_t)((kbase>>5) + (lane&1))*NN + m0 + wid*32 + (lane>>1));

#define GSTAGE(BUF, T) do { \
    _Pragma("unroll") \
    for (int is=0; is<2; ++is) \
      __builtin_amdgcn_global_load_lds((const __attribute__((address_space(1))) void*)(ytb[is] + (T)*128), \
          (__attribute__((address_space(3))) void*)&ldsB[BUF][wid*2048 + is*1024], 16, 0, 0); \
    __builtin_amdgcn_global_load_lds((const __attribute__((address_space(1))) void*)(mkb + (size_t)(T)*65536), \
        (__attribute__((address_space(3))) void*)&ldsM[BUF][wid*64], 4, 0, 0); \
  } while(0)

#define COMPUTE(BUF) do { \
    short8 bfrag[2][4]; \
    _Pragma("unroll") \
    for (int kk=0; kk<2; ++kk) \
      _Pragma("unroll") \
      for (int nf=0; nf<4; ++nf){ \
        int row = wn*64 + nf*16 + r; \
        bfrag[kk][nf] = *reinterpret_cast<const short8*>(&ldsB[BUF][row*128 + (((kk*4+g) ^ (row&7))<<4)]); \
      } \
    __builtin_amdgcn_s_setprio(1); \
    _Pragma("unroll") \
    for (int mf=0; mf<4; ++mf){ \
      int rowm = wm*64 + mf*16 + r; \
      u64 mw = *reinterpret_cast<const u64*>(&ldsM[BUF][rowm*2]); \
      _Pragma("unroll") \
      for (int kk=0; kk<2; ++kk){ \
        u32 byte = ((u32)(mw >> (kk*32)) >> (g*8)) & 0xffu; \
        u32 x = byte * 0x8001u; \
        u32x4 wv; \
        _Pragma("unroll") \
        for (int pp=0; pp<4; ++pp) wv[pp] = ((x >> (2*pp)) & 0x00010001u) * 0x3F80u; \
        short8 a = __builtin_bit_cast(short8, wv); \
        _Pragma("unroll") \
        for (int nf=0; nf<4; ++nf) \
          acc[mf][nf] = __builtin_amdgcn_mfma_f32_16x16x32_bf16(a, bfrag[kk][nf], acc[mf][nf], 0, 0, 0); \
      } \
    } \
    __builtin_amdgcn_s_setprio(0); \
  } while(0)

#define BODY(CB, SB, T) do { \
    GSTAGE(SB, (T)+2); \
    COMPUTE(CB); \
    VMCNT(3); \
    __builtin_amdgcn_s_barrier(); \
  } while(0)

  GSTAGE(0, 0);
  GSTAGE(1, 1);
  VMCNT(3);
  __builtin_amdgcn_s_barrier();

  #pragma unroll 1
  for (int t = 0; t < 12; t += 3){
    BODY(0, 2, t);
    BODY(1, 0, t+1);
    BODY(2, 1, t+2);
  }
  BODY(0, 2, 12);
  BODY(1, 0, 13);
  COMPUTE(2);
  VMCNT(0);
  __builtin_amdgcn_s_barrier();
  COMPUTE(0);

#undef GSTAGE
#undef COMPUTE
#undef BODY

  u16* dst = part + (size_t)zz * (NN*256);
  #pragma unroll
  for (int mf=0; mf<4; mf++)
    #pragma unroll
    for (int nf=0; nf<4; nf++)
      #pragma unroll
      for (int q=0;q<4;q++){
        int row = m0 + wm*64 + mf*16 + g*4 + q;
        int col = n0 + wn*64 + nf*16 + r;
        dst[row*256 + col] = f2bf(acc[mf][nf][q]);
      }
}

// ---- K5: out = bias + sum_z bf16 partial[z] ----
__global__ __launch_bounds__(256) void k_reduce(const u16* __restrict__ part, const float* __restrict__ bias,
                                                float* __restrict__ out){
  int i = blockIdx.x*256 + threadIdx.x;
  float4 bb = reinterpret_cast<const float4*>(bias)[i & 63];
  float a0 = bb.x, a1 = bb.y, a2 = bb.z, a3 = bb.w;
  #pragma unroll
  for (int z=0; z<8; ++z){
    u64 v = *reinterpret_cast<const u64*>(part + (size_t)z*2097152 + (size_t)i*4);
    a0 += bf2f((u16)(v      ));
    a1 += bf2f((u16)(v >> 16));
    a2 += bf2f((u16)(v >> 32));
    a3 += bf2f((u16)(v >> 48));
  }
  float4 o; o.x=a0; o.y=a1; o.z=a2; o.w=a3;
  reinterpret_cast<float4*>(out)[i] = o;
}

extern "C" void kernel_launch(void* const* d_in, const int* in_sizes, int n_in,
                              void* d_out, int out_size, void* d_ws, size_t ws_size,
                              hipStream_t stream) {
  const float* X    = (const float*)d_in[0];
  const float* S    = (const float*)d_in[1];
  const float* W    = (const float*)d_in[2];
  const float* bias = (const float*)d_in[3];
  float* out = (float*)d_out;
  char* ws = (char*)d_ws;
  u32*   maskT = (u32*)  (ws + 0);         //  8 MiB  [256 jwords][8192 i]
  u16*   Yt    = (u16*)  (ws + 8388608);   //  4 MiB  bf16 [256 f][8192 j]
  u16*   snHL  = (u16*)  (ws + 12582912);  // 512 KiB bf16 hi/lo split states
  float* dinvF = (float*)(ws + 13107200);  //  32 KiB
  u16*   part  = (u16*)  (ws + 13139968);  //  32 MiB bf16 [8][8192][256]

  k_norm  <<<dim3(32),   dim3(256), 0, stream>>>(S, snHL);
  k_maskM2<<<dim3(1024), dim3(256), 0, stream>>>(snHL, maskT);
  k_deg   <<<dim3(256),  dim3(256), 0, stream>>>(maskT, dinvF);
  k_ygemm <<<dim3(8,64), dim3(128), 0, stream>>>(X, W, dinvF, Yt);
  k_agg   <<<dim3(512),  dim3(512), 0, stream>>>(Yt, maskT, part);
  k_reduce<<<dim3(2048), dim3(256), 0, stream>>>(part, bias, out);
}